// Round 8
// baseline (242.043 us; speedup 1.0000x reference)
//
#include <hip/hip_runtime.h>
#include <stdint.h>

#define DIM 1024
#define GLOBAL_AS __attribute__((address_space(1)))
#define LDS_AS __attribute__((address_space(3)))

typedef short bf16x8 __attribute__((ext_vector_type(8)));
typedef float f32x4 __attribute__((ext_vector_type(4)));

// deg-4 Taylor via depth-2: R = I + A + A2/2 + (C3*A + C4*A2)*A2
#define C3f 0.16666667f
#define C4f 0.041666668f

__device__ __forceinline__ unsigned short f32_to_bf16(float f) {
    union { float f; uint32_t u; } v; v.f = f;
    uint32_t u = v.u;
    u += 0x7FFFu + ((u >> 16) & 1u);   // round-to-nearest-even
    return (unsigned short)(u >> 16);
}
__device__ __forceinline__ float bf16_to_f32(unsigned short u) {
    union { uint32_t u; float f; } v; v.u = ((uint32_t)u) << 16;
    return v.f;
}

// async global->LDS, 16B per lane; LDS dst = wave-uniform base + lane*16.
__device__ __forceinline__ void async16(const void* g, void* l) {
    __builtin_amdgcn_global_load_lds((GLOBAL_AS const void*)g,
                                     (LDS_AS void*)l, 16, 0, 0);
}

// Manual device barrier (monotonic counter, zeroed per launch by memset).
// Writer side: __syncthreads drains this block's writes to L2; tid0's
// __threadfence() (device scope) publishes across XCD L2s; atomic arrive.
// Reader side: acquire spin, then device fence + __syncthreads.
// Deadlock-free: only chain blocks (256) wait; they fit residency (2/CU x
// 256 CU = 512 at 64 KB LDS), and non-waiting convert blocks always retire.
__device__ __forceinline__ void gbar(unsigned* ctr, unsigned target) {
    __syncthreads();
    if (threadIdx.x == 0) {
        __threadfence();
        __hip_atomic_fetch_add(ctr, 1u, __ATOMIC_ACQ_REL,
                               __HIP_MEMORY_SCOPE_AGENT);
        while (__hip_atomic_load(ctr, __ATOMIC_ACQUIRE,
                                 __HIP_MEMORY_SCOPE_AGENT) < target)
            __builtin_amdgcn_s_sleep(8);
        __threadfence();
    }
    __syncthreads();
}

// ---- ONE regular kernel for the whole R-chain (R8) ----
// 512 blocks x 256 threads. Blocks [0,256): chain with 2 device barriers:
//   S0: A = W - W^T (bf16 Ab, G = -A), 4 tiles/block        [k_init body]
//   S1: A2 = A*A full-K; epilogue A2b = bf16(A2), Pb = bf16(C3*A + C4*A2)
//   S2: T = P*A2 full-K; epilogue R = T + I + A + A2/2 -> R^T bf16 (Rtb)
// Blocks [256,512): convert all X fp32 -> Xb bf16 (no barrier participation;
// kernel completion orders Xb before k_biggemm).
// Rationale: R4-R6 showed the chain (5-6 small serial launches, each <41 us)
// costs ~110-124 us total; this removes the launch/drain boundaries with a
// plain kernel (R7's hipLaunchCooperativeKernel failed; this needs no API).
__global__ __launch_bounds__(256, 2) void k_chain(
        const float* __restrict__ W, const float* __restrict__ X,
        unsigned short* __restrict__ Ab, unsigned short* __restrict__ G,
        unsigned short* __restrict__ A2b, unsigned short* __restrict__ Pb,
        unsigned short* __restrict__ Rtb, unsigned short* __restrict__ Xb,
        unsigned* __restrict__ bar) {
    int bid = blockIdx.x, tid = threadIdx.x;

    if (bid >= 256) {                 // ---- convert path: all of X -> Xb ----
        int b = bid - 256;            // 256 blocks x 256 thr x 32 chunks x 8
        #pragma unroll 4
        for (int it = 0; it < 32; it++) {
            size_t id = (size_t)it * 65536 + (size_t)b * 256 + tid;
            const f32x4* p = (const f32x4*)(X + id * 8);
            f32x4 v0 = p[0], v1 = p[1];
            unsigned short o[8];
            #pragma unroll
            for (int q = 0; q < 4; q++) { o[q] = f32_to_bf16(v0[q]); o[4 + q] = f32_to_bf16(v1[q]); }
            *(bf16x8*)&Xb[id * 8] = *(bf16x8*)o;
        }
        return;
    }

    __shared__ unsigned short lA[64 * 256];   // 32 KB
    __shared__ unsigned short lB[64 * 256];   // 32 KB
    int lane = tid & 63, w = tid >> 6;
    int wr = w >> 1, wc = w & 1;
    int rr = lane & 15, ko = lane >> 4;

    // ---- S0: A = W - W^T via 32x32 LDS transpose, 4 tiles/block ----
    {
        float (*t2)[33] = (float(*)[33])lA;   // 4.2 KB alias
        int tx = tid & 31, ty = tid >> 5;
        #pragma unroll
        for (int rep = 0; rep < 4; rep++) {
            int tile = bid * 4 + rep;
            int i0 = (tile & 31) * 32, j0 = (tile >> 5) * 32;
            float t1[4];
            #pragma unroll
            for (int p = 0; p < 4; p++) {
                int r = p * 8 + ty;
                t1[p] = W[(i0 + r) * DIM + j0 + tx];        // coalesced
                t2[r][tx] = W[(j0 + r) * DIM + i0 + tx];    // coalesced
            }
            __syncthreads();
            #pragma unroll
            for (int p = 0; p < 4; p++) {
                int r = p * 8 + ty;
                float a = t1[p] - t2[tx][r];                // W[i][j]-W[j][i]
                int gi = (i0 + r) * DIM + j0 + tx;
                Ab[gi] = f32_to_bf16(a);
                G[gi]  = f32_to_bf16(-a);
            }
            __syncthreads();
        }
    }
    gbar(bar, 256);

    int m0 = (bid & 15) * 64, n0 = (bid >> 4) * 64;

    // ---- S1: A2 = A * A (G rows = A^T = B-operand); epilogue A2b, Pb ----
    {
        f32x4 acc[2][2] = {};
        for (int ks = 0; ks < 4; ks++) {
            int kb = ks * 256;
            #pragma unroll
            for (int i = 0; i < 8; i++) {
                int l = i * 256 + tid;        // 0..2047 = 64 rows x 32 chunks
                int r = l >> 5, cst = l & 31;
                int cd = cst ^ (r & 7);
                async16(&Ab[(m0 + r) * DIM + kb + cd * 8], &lA[l * 8]);
                async16(&G[(n0 + r) * DIM + kb + cd * 8], &lB[l * 8]);
            }
            __syncthreads();
            #pragma unroll
            for (int s = 0; s < 8; s++) {
                int cd = s * 4 + ko;
                bf16x8 af[2], bq[2];
                #pragma unroll
                for (int mi = 0; mi < 2; mi++) {
                    int ra = wr * 32 + mi * 16 + rr;
                    af[mi] = *(const bf16x8*)&lA[ra * 256 + ((cd ^ (ra & 7)) * 8)];
                }
                #pragma unroll
                for (int ni = 0; ni < 2; ni++) {
                    int rb = wc * 32 + ni * 16 + rr;
                    bq[ni] = *(const bf16x8*)&lB[rb * 256 + ((cd ^ (rb & 7)) * 8)];
                }
                #pragma unroll
                for (int mi = 0; mi < 2; mi++)
                    #pragma unroll
                    for (int ni = 0; ni < 2; ni++)
                        acc[mi][ni] = __builtin_amdgcn_mfma_f32_16x16x32_bf16(
                            af[mi], bq[ni], acc[mi][ni], 0, 0, 0);
            }
            __syncthreads();
        }
        #pragma unroll
        for (int mi = 0; mi < 2; mi++)
            #pragma unroll
            for (int ni = 0; ni < 2; ni++)
                #pragma unroll
                for (int q = 0; q < 4; q++) {
                    int rl = wr * 32 + mi * 16 + ko * 4 + q;
                    int cl = wc * 32 + ni * 16 + rr;
                    int gi = (m0 + rl) * DIM + n0 + cl;
                    float v = acc[mi][ni][q];
                    A2b[gi] = f32_to_bf16(v);
                    float a = bf16_to_f32(Ab[gi]);
                    Pb[gi] = f32_to_bf16(C3f * a + C4f * v);
                }
    }
    gbar(bar, 512);

    // ---- S2: T = P * A2 (A2 symmetric -> Qt = A2b rows); epilogue R^T ----
    {
        f32x4 acc[2][2] = {};
        for (int ks = 0; ks < 4; ks++) {
            int kb = ks * 256;
            #pragma unroll
            for (int i = 0; i < 8; i++) {
                int l = i * 256 + tid;
                int r = l >> 5, cst = l & 31;
                int cd = cst ^ (r & 7);
                async16(&Pb[(m0 + r) * DIM + kb + cd * 8], &lA[l * 8]);
                async16(&A2b[(n0 + r) * DIM + kb + cd * 8], &lB[l * 8]);
            }
            __syncthreads();
            #pragma unroll
            for (int s = 0; s < 8; s++) {
                int cd = s * 4 + ko;
                bf16x8 af[2], bq[2];
                #pragma unroll
                for (int mi = 0; mi < 2; mi++) {
                    int ra = wr * 32 + mi * 16 + rr;
                    af[mi] = *(const bf16x8*)&lA[ra * 256 + ((cd ^ (ra & 7)) * 8)];
                }
                #pragma unroll
                for (int ni = 0; ni < 2; ni++) {
                    int rb = wc * 32 + ni * 16 + rr;
                    bq[ni] = *(const bf16x8*)&lB[rb * 256 + ((cd ^ (rb & 7)) * 8)];
                }
                #pragma unroll
                for (int mi = 0; mi < 2; mi++)
                    #pragma unroll
                    for (int ni = 0; ni < 2; ni++)
                        acc[mi][ni] = __builtin_amdgcn_mfma_f32_16x16x32_bf16(
                            af[mi], bq[ni], acc[mi][ni], 0, 0, 0);
            }
            __syncthreads();
        }
        // R = acc + I + A + A2/2; LDS-transpose; Rtb = bf16(R^T)
        float* tb = (float*)lA;               // 64*65*4 = 16.6 KB
        #pragma unroll
        for (int mi = 0; mi < 2; mi++)
            #pragma unroll
            for (int ni = 0; ni < 2; ni++)
                #pragma unroll
                for (int q = 0; q < 4; q++) {
                    int rl = wr * 32 + mi * 16 + ko * 4 + q;
                    int cl = wc * 32 + ni * 16 + rr;
                    int gi = (m0 + rl) * DIM + n0 + cl;
                    float a = bf16_to_f32(Ab[gi]);
                    float a2 = bf16_to_f32(A2b[gi]);
                    float d = (m0 + rl == n0 + cl) ? 1.0f : 0.0f;
                    tb[cl * 65 + rl] = acc[mi][ni][q] + d + a + 0.5f * a2;
                }
        __syncthreads();
        #pragma unroll
        for (int q = 0; q < 16; q++) {
            int l = tid * 16 + q;
            int orow = l >> 6, ocol = l & 63;
            Rtb[(n0 + orow) * DIM + m0 + ocol] = f32_to_bf16(tb[orow * 65 + ocol]);
        }
    }
}

// Out(16384x1024) = Xb(bf16) @ R, R^T row-major bf16 (Rtb).
// R5-measured winner (41 us, MfmaUtil ~31%): 128x128 tiles, BK=64, 32 KB LDS,
// grid 1024 = 4 blocks/CU; bid%8 == m%8 keeps an m-strip's n-tiles on one XCD.
__global__ __launch_bounds__(256, 4) void k_biggemm(
        const unsigned short* __restrict__ Xb,
        const unsigned short* __restrict__ Rtb,
        float* __restrict__ Out) {
    __shared__ unsigned short lX[128 * 64];   // 16 KB
    __shared__ unsigned short lB[128 * 64];   // 16 KB
    int tid = threadIdx.x;
    int bid = blockIdx.x;
    int m0 = (bid & 127) * 128, n0 = (bid >> 7) * 128;
    int lane = tid & 63, w = tid >> 6;
    int wr = w >> 1, wc = w & 1;
    int rr = lane & 15, ko = lane >> 4;
    f32x4 acc[4][4] = {};
    for (int kb = 0; kb < DIM; kb += 64) {
        #pragma unroll
        for (int i = 0; i < 4; i++) {         // 128 rows x 8 chunks each array
            int l = i * 256 + tid;
            int r = l >> 3, cst = l & 7;
            int cd = cst ^ (r & 7);
            async16(&Xb[(size_t)(m0 + r) * DIM + kb + cd * 8], &lX[l * 8]);
            async16(&Rtb[(n0 + r) * DIM + kb + cd * 8], &lB[l * 8]);
        }
        __syncthreads();
        #pragma unroll
        for (int s = 0; s < 2; s++) {
            int cd = s * 4 + ko;
            bf16x8 af[4], bq[4];
            #pragma unroll
            for (int mi = 0; mi < 4; mi++) {
                int ra = wr * 64 + mi * 16 + rr;
                af[mi] = *(const bf16x8*)&lX[ra * 64 + ((cd ^ (ra & 7)) * 8)];
            }
            #pragma unroll
            for (int ni = 0; ni < 4; ni++) {
                int rb = wc * 64 + ni * 16 + rr;
                bq[ni] = *(const bf16x8*)&lB[rb * 64 + ((cd ^ (rb & 7)) * 8)];
            }
            #pragma unroll
            for (int mi = 0; mi < 4; mi++)
                #pragma unroll
                for (int ni = 0; ni < 4; ni++)
                    acc[mi][ni] = __builtin_amdgcn_mfma_f32_16x16x32_bf16(
                        af[mi], bq[ni], acc[mi][ni], 0, 0, 0);
        }
        __syncthreads();
    }
    #pragma unroll
    for (int mi = 0; mi < 4; mi++)
        #pragma unroll
        for (int ni = 0; ni < 4; ni++)
            #pragma unroll
            for (int q = 0; q < 4; q++) {
                int row = m0 + wr * 64 + mi * 16 + ko * 4 + q;
                int col = n0 + wc * 64 + ni * 16 + rr;
                Out[(size_t)row * DIM + col] = acc[mi][ni][q];
            }
}

extern "C" void kernel_launch(void* const* d_in, const int* in_sizes, int n_in,
                              void* d_out, int out_size, void* d_ws, size_t ws_size,
                              hipStream_t stream) {
    const float* X = (const float*)d_in[0];        // 4*4096*1024 fp32
    const float* W = (const float*)d_in[1];        // 1024*1024 fp32
    float* Out = (float*)d_out;                    // 16384*1024 fp32
    char* ws = (char*)d_ws;
    const size_t MB = 1u << 20;
    unsigned short* Ab  = (unsigned short*)(ws + 0 * MB);
    unsigned short* G   = (unsigned short*)(ws + 2 * MB);
    unsigned short* A2b = (unsigned short*)(ws + 4 * MB);
    unsigned short* Pb  = (unsigned short*)(ws + 6 * MB);
    unsigned short* Rtb = (unsigned short*)(ws + 8 * MB);
    unsigned short* Xb  = (unsigned short*)(ws + 10 * MB);  // 32 MB -> ends 42 MB
    unsigned* bar = (unsigned*)(ws + 42 * MB);              // 8 B counter

    // zero the barrier counter (stream-ordered, graph-capturable)
    hipMemsetAsync(bar, 0, 8, stream);
    // whole R-chain + X conversion in one launch (2 device barriers inside)
    k_chain<<<512, 256, 0, stream>>>(W, X, Ab, G, A2b, Pb, Rtb, Xb, bar);
    // big GEMM: 1024 blocks (128 m x 8 n), 128x128 tiles, 4 blocks/CU.
    k_biggemm<<<1024, 256, 0, stream>>>(Xb, Rtb, Out);
}

// Round 9
// 162.484 us; speedup vs baseline: 1.4896x; 1.4896x over previous
//
#include <hip/hip_runtime.h>
#include <stdint.h>

#define DIM 1024
#define GLOBAL_AS __attribute__((address_space(1)))
#define LDS_AS __attribute__((address_space(3)))

typedef short bf16x8 __attribute__((ext_vector_type(8)));
typedef float f32x4 __attribute__((ext_vector_type(4)));

// deg-4 Taylor via depth-2: R = I + A + A2/2 + (C3*A + C4*A2)*A2
#define C3f 0.16666667f
#define C4f 0.041666668f

__device__ __forceinline__ unsigned short f32_to_bf16(float f) {
    union { float f; uint32_t u; } v; v.f = f;
    uint32_t u = v.u;
    u += 0x7FFFu + ((u >> 16) & 1u);   // round-to-nearest-even
    return (unsigned short)(u >> 16);
}
__device__ __forceinline__ float bf16_to_f32(unsigned short u) {
    union { uint32_t u; float f; } v; v.u = ((uint32_t)u) << 16;
    return v.f;
}

// async global->LDS, 16B per lane; LDS dst = wave-uniform base + lane*16.
__device__ __forceinline__ void async16(const void* g, void* l) {
    __builtin_amdgcn_global_load_lds((GLOBAL_AS const void*)g,
                                     (LDS_AS void*)l, 16, 0, 0);
}

// Coalesced A = W - W^T via 32x32 LDS tile transpose.
// Ab = bf16(A) (A-operand), G = bf16(-A) = bf16(A^T) (B-operand).
__global__ __launch_bounds__(256) void k_init(const float* __restrict__ W,
        unsigned short* __restrict__ Ab, unsigned short* __restrict__ G) {
    __shared__ float t2[32][33];
    int i0 = (blockIdx.x & 31) * 32, j0 = (blockIdx.x >> 5) * 32;
    int tx = threadIdx.x & 31, ty = threadIdx.x >> 5;
    float t1[4];
    #pragma unroll
    for (int p = 0; p < 4; p++) {
        int r = p * 8 + ty;
        t1[p] = W[(i0 + r) * DIM + j0 + tx];            // coalesced
        t2[r][tx] = W[(j0 + r) * DIM + i0 + tx];        // coalesced
    }
    __syncthreads();
    #pragma unroll
    for (int p = 0; p < 4; p++) {
        int r = p * 8 + ty;
        float a = t1[p] - t2[tx][r];                    // W[i][j] - W[j][i]
        int gi = (i0 + r) * DIM + j0 + tx;
        Ab[gi] = f32_to_bf16(a);
        G[gi]  = f32_to_bf16(-a);
    }
}

// R9 small-GEMM: 32x32 tiles -> 1024 GEMM blocks (4 blocks/CU, 32 KB LDS).
// R8's profile showed the chain GEMMs at 256 blocks = 1 block/CU ran at ~1%
// utilization (stage -> vmcnt(0) drain -> compute, nothing overlapping).
// 4 blocks/CU gives cross-block stage/compute overlap — the same mechanism
// that makes k_biggemm (4/CU) 6x more BW-efficient. Per wave: one 16x16 frag.
// MODE 1 (k_g1): out1 = bf16(acc) = A2; out2 = bf16(C3*A + C4*acc) = P
// MODE 2 (k_g2): v = acc + I + A + A2/2; LDS-transpose; out1 = bf16(v^T)
// Fused: blocks [0,1024) GEMM; blocks [1024, 1024+4096) convert X half.
template<int MODE>
__device__ __forceinline__ void gemm_chain_body(
        const unsigned short* __restrict__ P,
        const unsigned short* __restrict__ Qt,
        const unsigned short* __restrict__ Ab,
        const unsigned short* __restrict__ A2b,
        unsigned short* __restrict__ out1,
        unsigned short* __restrict__ out2,
        const float* __restrict__ X,
        unsigned short* __restrict__ Xb,
        size_t xoff) {
    int bid = blockIdx.x;
    int tid = threadIdx.x;
    if (bid >= 1024) {                       // ---- convert path (4096 blocks) ----
        size_t id = (size_t)(bid - 1024) * 256 + tid;
        const f32x4* p = (const f32x4*)(X + xoff + id * 8);
        f32x4 v0 = p[0], v1 = p[1];
        unsigned short o[8];
        #pragma unroll
        for (int q = 0; q < 4; q++) { o[q] = f32_to_bf16(v0[q]); o[4 + q] = f32_to_bf16(v1[q]); }
        *(bf16x8*)&Xb[xoff + id * 8] = *(bf16x8*)o;
        return;
    }
    __shared__ unsigned short lA[32 * 256];   // 16 KB
    __shared__ unsigned short lB[32 * 256];   // 16 KB
    int m0 = (bid & 31) * 32, n0 = (bid >> 5) * 32;
    int lane = tid & 63, w = tid >> 6;
    int wr = w >> 1, wc = w & 1;              // 2x2 wave grid, 16x16 each
    int rr = lane & 15, ko = lane >> 4;
    f32x4 acc = {};
    for (int ks = 0; ks < 4; ks++) {
        int kb = ks * 256;
        #pragma unroll
        for (int i = 0; i < 4; i++) {
            int l = i * 256 + tid;            // 0..1023 = 32 rows x 32 chunks
            int r = l >> 5, cst = l & 31;
            int cd = cst ^ (r & 7);
            async16(&P[(m0 + r) * DIM + kb + cd * 8], &lA[l * 8]);
            async16(&Qt[(n0 + r) * DIM + kb + cd * 8], &lB[l * 8]);
        }
        __syncthreads();
        #pragma unroll
        for (int s = 0; s < 8; s++) {
            int cd = s * 4 + ko;
            int ra = wr * 16 + rr;
            int rb = wc * 16 + rr;
            bf16x8 af = *(const bf16x8*)&lA[ra * 256 + ((cd ^ (ra & 7)) * 8)];
            bf16x8 bq = *(const bf16x8*)&lB[rb * 256 + ((cd ^ (rb & 7)) * 8)];
            acc = __builtin_amdgcn_mfma_f32_16x16x32_bf16(af, bq, acc, 0, 0, 0);
        }
        __syncthreads();
    }
    if (MODE == 1) {
        #pragma unroll
        for (int q = 0; q < 4; q++) {
            int rl = wr * 16 + ko * 4 + q;
            int cl = wc * 16 + rr;
            int gi = (m0 + rl) * DIM + n0 + cl;
            float v = acc[q];
            out1[gi] = f32_to_bf16(v);
            float a = bf16_to_f32(Ab[gi]);
            out2[gi] = f32_to_bf16(C3f * a + C4f * v);
        }
    } else {
        float* tb = (float*)lA;               // 32*33*4 = 4.2 KB
        #pragma unroll
        for (int q = 0; q < 4; q++) {
            int rl = wr * 16 + ko * 4 + q;
            int cl = wc * 16 + rr;
            int gi = (m0 + rl) * DIM + n0 + cl;
            float a = bf16_to_f32(Ab[gi]);
            float a2 = bf16_to_f32(A2b[gi]);
            float d = (m0 + rl == n0 + cl) ? 1.0f : 0.0f;
            tb[cl * 33 + rl] = acc[q] + d + a + 0.5f * a2;
        }
        __syncthreads();
        #pragma unroll
        for (int q = 0; q < 4; q++) {
            int l = tid * 4 + q;              // 1024 elements
            int orow = l >> 5, ocol = l & 31;
            out1[(n0 + orow) * DIM + m0 + ocol] = f32_to_bf16(tb[orow * 33 + ocol]);
        }
    }
}

__global__ __launch_bounds__(256, 4) void k_g1(
        const unsigned short* __restrict__ Ab, const unsigned short* __restrict__ G,
        unsigned short* __restrict__ A2b, unsigned short* __restrict__ Pb,
        const float* __restrict__ X, unsigned short* __restrict__ Xb) {
    gemm_chain_body<1>(Ab, G, Ab, nullptr, A2b, Pb, X, Xb, 0);
}

__global__ __launch_bounds__(256, 4) void k_g2(
        const unsigned short* __restrict__ Pb, const unsigned short* __restrict__ A2b,
        const unsigned short* __restrict__ Ab, unsigned short* __restrict__ Rtb,
        const float* __restrict__ X, unsigned short* __restrict__ Xb) {
    // A2^T = A2 (symmetric), so Qt = A2b row-major directly.
    gemm_chain_body<2>(Pb, A2b, Ab, A2b, Rtb, nullptr, X, Xb, (size_t)8388608);
}

// Out(16384x1024) = Xb(bf16) @ R, R^T row-major bf16 (Rtb).
// R5-measured winner (41 us, MfmaUtil ~31%): 128x128 tiles, BK=64, 32 KB LDS,
// grid 1024 = 4 blocks/CU; bid%8 == m%8 keeps an m-strip's n-tiles on one XCD.
__global__ __launch_bounds__(256, 4) void k_biggemm(
        const unsigned short* __restrict__ Xb,
        const unsigned short* __restrict__ Rtb,
        float* __restrict__ Out) {
    __shared__ unsigned short lX[128 * 64];   // 16 KB
    __shared__ unsigned short lB[128 * 64];   // 16 KB
    int tid = threadIdx.x;
    int bid = blockIdx.x;
    int m0 = (bid & 127) * 128, n0 = (bid >> 7) * 128;
    int lane = tid & 63, w = tid >> 6;
    int wr = w >> 1, wc = w & 1;
    int rr = lane & 15, ko = lane >> 4;
    f32x4 acc[4][4] = {};
    for (int kb = 0; kb < DIM; kb += 64) {
        #pragma unroll
        for (int i = 0; i < 4; i++) {         // 128 rows x 8 chunks each array
            int l = i * 256 + tid;
            int r = l >> 3, cst = l & 7;
            int cd = cst ^ (r & 7);
            async16(&Xb[(size_t)(m0 + r) * DIM + kb + cd * 8], &lX[l * 8]);
            async16(&Rtb[(n0 + r) * DIM + kb + cd * 8], &lB[l * 8]);
        }
        __syncthreads();
        #pragma unroll
        for (int s = 0; s < 2; s++) {
            int cd = s * 4 + ko;
            bf16x8 af[4], bq[4];
            #pragma unroll
            for (int mi = 0; mi < 4; mi++) {
                int ra = wr * 64 + mi * 16 + rr;
                af[mi] = *(const bf16x8*)&lX[ra * 64 + ((cd ^ (ra & 7)) * 8)];
            }
            #pragma unroll
            for (int ni = 0; ni < 4; ni++) {
                int rb = wc * 64 + ni * 16 + rr;
                bq[ni] = *(const bf16x8*)&lB[rb * 64 + ((cd ^ (rb & 7)) * 8)];
            }
            #pragma unroll
            for (int mi = 0; mi < 4; mi++)
                #pragma unroll
                for (int ni = 0; ni < 4; ni++)
                    acc[mi][ni] = __builtin_amdgcn_mfma_f32_16x16x32_bf16(
                        af[mi], bq[ni], acc[mi][ni], 0, 0, 0);
        }
        __syncthreads();
    }
    #pragma unroll
    for (int mi = 0; mi < 4; mi++)
        #pragma unroll
        for (int ni = 0; ni < 4; ni++)
            #pragma unroll
            for (int q = 0; q < 4; q++) {
                int row = m0 + wr * 64 + mi * 16 + ko * 4 + q;
                int col = n0 + wc * 64 + ni * 16 + rr;
                Out[(size_t)row * DIM + col] = acc[mi][ni][q];
            }
}

extern "C" void kernel_launch(void* const* d_in, const int* in_sizes, int n_in,
                              void* d_out, int out_size, void* d_ws, size_t ws_size,
                              hipStream_t stream) {
    const float* X = (const float*)d_in[0];        // 4*4096*1024 fp32
    const float* W = (const float*)d_in[1];        // 1024*1024 fp32
    float* Out = (float*)d_out;                    // 16384*1024 fp32
    char* ws = (char*)d_ws;
    const size_t MB = 1u << 20;
    unsigned short* Ab  = (unsigned short*)(ws + 0 * MB);
    unsigned short* G   = (unsigned short*)(ws + 2 * MB);
    unsigned short* A2b = (unsigned short*)(ws + 4 * MB);
    unsigned short* Pb  = (unsigned short*)(ws + 6 * MB);
    unsigned short* Rtb = (unsigned short*)(ws + 8 * MB);
    unsigned short* Xb  = (unsigned short*)(ws + 10 * MB);  // 32 MB

    k_init<<<1024, 256, 0, stream>>>(W, Ab, G);
    // g1: A2 = A*A, P = C3*A + C4*A2; + convert X[0 : 8M). 1024 GEMM blocks.
    k_g1<<<1024 + 4096, 256, 0, stream>>>(Ab, G, A2b, Pb, X, Xb);
    // g2: T = P*A2; R = I + A + A2/2 + T -> R^T bf16; + convert X[8M : 16M)
    k_g2<<<1024 + 4096, 256, 0, stream>>>(Pb, A2b, Ab, Rtb, X, Xb);
    // big GEMM: 1024 blocks (128 m x 8 n), 128x128 tiles, 4 blocks/CU.
    k_biggemm<<<1024, 256, 0, stream>>>(Xb, Rtb, Out);
}